// Round 6
// baseline (116.349 us; speedup 1.0000x reference)
//
#include <hip/hip_runtime.h>

#define NPATCH 16384
#define NDB    16384
#define WS9    9
#define KP     16               // K padded 9 -> 16 for 32x32x16 MFMA
#define JCH    32               // db chunks (grid.y)
#define CHUNK  (NDB / JCH)      // 512 rows per chunk
#define TILES  (CHUNK / 32)     // 16 j-tiles per chunk
#define BAND_LO 0.8998f         // 0.9 - 2e-4  (split-bf16 err < ~5e-6)
#define BAND_HI 0.9002f         // 0.9 + 2e-4

typedef short bf16x8 __attribute__((ext_vector_type(8)));
typedef float f32x16 __attribute__((ext_vector_type(16)));

// numpy-order norm of 9 elements: sqrt(pairwise-8 + remainder), no contraction.
__device__ __forceinline__ float np_norm9(const float* v) {
#pragma clang fp contract(off)
    float q0 = v[0] * v[0], q1 = v[1] * v[1], q2 = v[2] * v[2], q3 = v[3] * v[3];
    float q4 = v[4] * v[4], q5 = v[5] * v[5], q6 = v[6] * v[6], q7 = v[7] * v[7];
    float q8 = v[8] * v[8];
    float s = ((q0 + q1) + (q2 + q3)) + ((q4 + q5) + (q6 + q7));
    s = s + q8;
    return sqrtf(s);
}

// fp32 -> bf16 RTNE (no NaN inputs here), and back
__device__ __forceinline__ unsigned short f2bf(float x) {
    unsigned u = __float_as_uint(x);
    return (unsigned short)((u + 0x7fffu + ((u >> 16) & 1u)) >> 16);
}
__device__ __forceinline__ float bf2f(unsigned short h) {
    return __uint_as_float(((unsigned)h) << 16);
}

// load row of 9, normalize, split to bf16 hi/lo, K-pad to 16, pack to LDS as
// 2x int4 per array via proper int arrays (R4's &int4 alias overflow fixed).
__device__ __forceinline__ void stage_row(const float* __restrict__ src,
                                          unsigned short* dh, unsigned short* dl) {
    float v[WS9];
#pragma unroll
    for (int k = 0; k < WS9; k++) v[k] = src[k];
    float inv = 1.0f / np_norm9(v);
    unsigned short h[KP], l[KP];
#pragma unroll
    for (int k = 0; k < KP; k++) {
        float x = (k < WS9) ? v[k] * inv : 0.0f;
        h[k] = f2bf(x);
        l[k] = f2bf(x - bf2f(h[k]));
    }
    int hw[8], lw[8];
#pragma unroll
    for (int k = 0; k < 8; k++) {
        hw[k] = (int)h[2 * k] | ((int)h[2 * k + 1] << 16);
        lw[k] = (int)l[2 * k] | ((int)l[2 * k + 1] << 16);
    }
    ((int4*)dh)[0] = make_int4(hw[0], hw[1], hw[2], hw[3]);
    ((int4*)dh)[1] = make_int4(hw[4], hw[5], hw[6], hw[7]);
    ((int4*)dl)[0] = make_int4(lw[0], lw[1], lw[2], lw[3]);
    ((int4*)dl)[1] = make_int4(lw[4], lw[5], lw[6], lw[7]);
}

// K1: fused prep + phase1 (unchanged from R5, proven absmax=0).
// Block = 256 patches (x) x 512-row db chunk (y). Splits in-block into LDS;
// dot = hi*hi + hi*lo + lo*hi via 32x32x16 bf16 MFMA; chunk cos-max plain-
// stored to partial[y][i].
__global__ __launch_bounds__(256) void k_phase1(const float* __restrict__ patches,
                                                const float* __restrict__ db,
                                                float* __restrict__ partial) {
    __shared__ __align__(16) unsigned short s_dnh[CHUNK * KP];
    __shared__ __align__(16) unsigned short s_dnl[CHUNK * KP];
    __shared__ __align__(16) unsigned short s_pnh[256 * KP];
    __shared__ __align__(16) unsigned short s_pnl[256 * KP];

    int jbase = blockIdx.y * CHUNK;
    int ibase = blockIdx.x * 256;
#pragma unroll
    for (int rr = 0; rr < CHUNK / 256; rr++) {
        int r = rr * 256 + threadIdx.x;
        stage_row(db + (size_t)(jbase + r) * WS9, &s_dnh[r * KP], &s_dnl[r * KP]);
    }
    stage_row(patches + (size_t)(ibase + threadIdx.x) * WS9,
              &s_pnh[threadIdx.x * KP], &s_pnl[threadIdx.x * KP]);
    __syncthreads();

    int lane = threadIdx.x & 63;
    int wave = threadIdx.x >> 6;
    int col = lane & 31;
    int half = lane >> 5;
    int i0 = ibase + wave * 64;

    const bf16x8* Ph = (const bf16x8*)s_pnh;   // 2 frags per 16-elem row
    const bf16x8* Pl = (const bf16x8*)s_pnl;
    bf16x8 b_hi0 = Ph[(wave * 64 + col) * 2 + half];
    bf16x8 b_lo0 = Pl[(wave * 64 + col) * 2 + half];
    bf16x8 b_hi1 = Ph[(wave * 64 + 32 + col) * 2 + half];
    bf16x8 b_lo1 = Pl[(wave * 64 + 32 + col) * 2 + half];

    const bf16x8* Ah = (const bf16x8*)s_dnh;
    const bf16x8* Al = (const bf16x8*)s_dnl;

    f32x16 zc = {0.f,0.f,0.f,0.f,0.f,0.f,0.f,0.f,0.f,0.f,0.f,0.f,0.f,0.f,0.f,0.f};
    float rm0 = -3.0e38f, rm1 = -3.0e38f;

#pragma unroll 2
    for (int t = 0; t < TILES; ++t) {
        bf16x8 a_h = Ah[(t * 32 + col) * 2 + half];
        bf16x8 a_l = Al[(t * 32 + col) * 2 + half];
        f32x16 acc0 = __builtin_amdgcn_mfma_f32_32x32x16_bf16(a_h, b_hi0, zc, 0, 0, 0);
        acc0 = __builtin_amdgcn_mfma_f32_32x32x16_bf16(a_h, b_lo0, acc0, 0, 0, 0);
        acc0 = __builtin_amdgcn_mfma_f32_32x32x16_bf16(a_l, b_hi0, acc0, 0, 0, 0);
        f32x16 acc1 = __builtin_amdgcn_mfma_f32_32x32x16_bf16(a_h, b_hi1, zc, 0, 0, 0);
        acc1 = __builtin_amdgcn_mfma_f32_32x32x16_bf16(a_h, b_lo1, acc1, 0, 0, 0);
        acc1 = __builtin_amdgcn_mfma_f32_32x32x16_bf16(a_l, b_hi1, acc1, 0, 0, 0);
#pragma unroll
        for (int r = 0; r < 16; ++r) {
            rm0 = fmaxf(rm0, acc0[r]);
            rm1 = fmaxf(rm1, acc1[r]);
        }
    }
    rm0 = fmaxf(rm0, __shfl_xor(rm0, 32, 64));
    rm1 = fmaxf(rm1, __shfl_xor(rm1, 32, 64));
    int ti = half ? (i0 + 32 + col) : (i0 + col);
    partial[(size_t)blockIdx.y * NPATCH + ti] = half ? rm1 : rm0;
}

// K2: merged finish. 64 blocks x 256 threads. Each block:
//  (a) copies its 576-float4 slice of db -> out,
//  (b) classifies its 256 patches from the 32 chunk partials; definite rows
//      written immediately, band patches collected in an LDS list,
//  (c) cooperatively re-checks each band patch with the exact numpy-mirror
//      arithmetic (verbatim from the proven phase2): sequential fmaf dot,
//      pairwise-8 norms, IEEE fp32 divide, f64 comparison vs 0.9.
__global__ __launch_bounds__(256) void k_finish(const float* __restrict__ patches,
                                                const float* __restrict__ db,
                                                const float* __restrict__ partial,
                                                float* __restrict__ out) {
    __shared__ int s_list[256];
    __shared__ int s_cnt;
    __shared__ int s_hit;
    if (threadIdx.x == 0) s_cnt = 0;
    __syncthreads();

    // (a) db copy: 36864 float4 over 64 blocks = 576 each
    {
        const float4* dbv = (const float4*)db;
        float4* outv = (float4*)out;
        int base = blockIdx.x * 576;
#pragma unroll
        for (int rr = 0; rr < 3; rr++) {
            int t = rr * 256 + (int)threadIdx.x;
            if (t < 576) outv[base + t] = dbv[base + t];
        }
    }

    // (b) classify
    int i = blockIdx.x * 256 + threadIdx.x;
    float cosmax = partial[i];
#pragma unroll
    for (int c = 1; c < JCH; c++)
        cosmax = fmaxf(cosmax, partial[(size_t)c * NPATCH + i]);
    if (cosmax >= BAND_LO && cosmax < BAND_HI) {
        int idx = atomicAdd(&s_cnt, 1);
        s_list[idx] = i;
    } else {
        int hit = (cosmax >= BAND_HI) ? 1 : 0;
#pragma unroll
        for (int k = 0; k < WS9; k++)
            out[(size_t)(NDB + i) * WS9 + k] = hit ? 0.0f : patches[(size_t)i * WS9 + k];
    }
    __syncthreads();

    // (c) exact recheck of this block's band patches
    int nb = s_cnt;
    for (int e = 0; e < nb; e++) {
        int ip = s_list[e];
        if (threadIdx.x == 0) s_hit = 0;
        __syncthreads();
        float p[WS9];
#pragma unroll
        for (int k = 0; k < WS9; k++) p[k] = patches[(size_t)ip * WS9 + k];
        float npn = np_norm9(p);
        int hit = 0;
        for (int j = (int)threadIdx.x; j < NDB; j += 256) {
            float d[WS9];
#pragma unroll
            for (int k = 0; k < WS9; k++) d[k] = db[(size_t)j * WS9 + k];
            float dot = 0.0f;
#pragma unroll
            for (int k = 0; k < WS9; k++) dot = fmaf(p[k], d[k], dot);
            float nd = np_norm9(d);
            float cs = dot / (npn * nd);          // IEEE fp32 divide
            if (!((double)cs < 0.9)) hit = 1;     // numpy promotes to f64
        }
        if (hit) atomicOr(&s_hit, 1);
        __syncthreads();
        int m = s_hit;
        if (threadIdx.x < WS9)
            out[(size_t)(NDB + ip) * WS9 + threadIdx.x] = m ? 0.0f : p[threadIdx.x];
        __syncthreads();
    }
}

extern "C" void kernel_launch(void* const* d_in, const int* in_sizes, int n_in,
                              void* d_out, int out_size, void* d_ws, size_t ws_size,
                              hipStream_t stream) {
    const float* patches = (const float*)d_in[0];  // [16384][9]
    const float* db      = (const float*)d_in[1];  // [16384][9]
    float* out = (float*)d_out;                    // [32768][9]

    // ws layout: partial (JCH*NPATCH f32 = 2 MB)
    float* partial = (float*)d_ws;

    k_phase1<<<dim3(NPATCH / 256, JCH), dim3(256), 0, stream>>>(patches, db, partial);
    k_finish<<<dim3(64), dim3(256), 0, stream>>>(patches, db, partial, out);
}

// Round 7
// 95.949 us; speedup vs baseline: 1.2126x; 1.2126x over previous
//
#include <hip/hip_runtime.h>

#define NPATCH 16384
#define NDB    16384
#define WS9    9
#define KP     16               // K padded 9 -> 16 for 32x32x16 MFMA
#define JCH    32               // db chunks (grid.y)
#define CHUNK  (NDB / JCH)      // 512 rows per chunk
#define TILES  (CHUNK / 32)     // 16 j-tiles per chunk
// Split-bf16 cosmax error vs numpy fp32 path <= ~6e-6 (lo*lo 3.8e-6 + accum
// 5e-7 + normalize 2e-7 + numpy's own ~1e-6). Band +-2e-5 keeps 3x margin;
// R6 lesson: band population ~= 16384 * 0.0075 * width, so +-2e-4 put ~800
// patches in recheck. +-2e-5 -> ~80.
#define BAND_LO 0.89998f
#define BAND_HI 0.90002f
#define COPY_BLOCKS 144         // NDB*9/4/256 float4-copy blocks

typedef short bf16x8 __attribute__((ext_vector_type(8)));
typedef float f32x16 __attribute__((ext_vector_type(16)));

// numpy-order norm of 9 elements: sqrt(pairwise-8 + remainder), no contraction.
__device__ __forceinline__ float np_norm9(const float* v) {
#pragma clang fp contract(off)
    float q0 = v[0] * v[0], q1 = v[1] * v[1], q2 = v[2] * v[2], q3 = v[3] * v[3];
    float q4 = v[4] * v[4], q5 = v[5] * v[5], q6 = v[6] * v[6], q7 = v[7] * v[7];
    float q8 = v[8] * v[8];
    float s = ((q0 + q1) + (q2 + q3)) + ((q4 + q5) + (q6 + q7));
    s = s + q8;
    return sqrtf(s);
}

// fp32 -> bf16 RTNE (no NaN inputs here), and back
__device__ __forceinline__ unsigned short f2bf(float x) {
    unsigned u = __float_as_uint(x);
    return (unsigned short)((u + 0x7fffu + ((u >> 16) & 1u)) >> 16);
}
__device__ __forceinline__ float bf2f(unsigned short h) {
    return __uint_as_float(((unsigned)h) << 16);
}

// load row of 9, normalize, split to bf16 hi/lo, K-pad to 16, pack to LDS as
// 2x int4 per array via proper int arrays (R4's &int4 alias overflow fixed).
__device__ __forceinline__ void stage_row(const float* __restrict__ src,
                                          unsigned short* dh, unsigned short* dl) {
    float v[WS9];
#pragma unroll
    for (int k = 0; k < WS9; k++) v[k] = src[k];
    float inv = 1.0f / np_norm9(v);
    unsigned short h[KP], l[KP];
#pragma unroll
    for (int k = 0; k < KP; k++) {
        float x = (k < WS9) ? v[k] * inv : 0.0f;
        h[k] = f2bf(x);
        l[k] = f2bf(x - bf2f(h[k]));
    }
    int hw[8], lw[8];
#pragma unroll
    for (int k = 0; k < 8; k++) {
        hw[k] = (int)h[2 * k] | ((int)h[2 * k + 1] << 16);
        lw[k] = (int)l[2 * k] | ((int)l[2 * k + 1] << 16);
    }
    ((int4*)dh)[0] = make_int4(hw[0], hw[1], hw[2], hw[3]);
    ((int4*)dh)[1] = make_int4(hw[4], hw[5], hw[6], hw[7]);
    ((int4*)dl)[0] = make_int4(lw[0], lw[1], lw[2], lw[3]);
    ((int4*)dl)[1] = make_int4(lw[4], lw[5], lw[6], lw[7]);
}

// K1: fused prep + phase1 (proven absmax=0 in R5).
// Block = 256 patches (x) x 512-row db chunk (y). Splits in-block into LDS;
// dot = hi*hi + hi*lo + lo*hi via 32x32x16 bf16 MFMA; chunk cos-max plain-
// stored to partial[y][i] (no atomics, no init).
__global__ __launch_bounds__(256) void k_phase1(const float* __restrict__ patches,
                                                const float* __restrict__ db,
                                                float* __restrict__ partial,
                                                int* __restrict__ band_count) {
    __shared__ __align__(16) unsigned short s_dnh[CHUNK * KP];
    __shared__ __align__(16) unsigned short s_dnl[CHUNK * KP];
    __shared__ __align__(16) unsigned short s_pnh[256 * KP];
    __shared__ __align__(16) unsigned short s_pnl[256 * KP];

    if (blockIdx.x == 0 && blockIdx.y == 0 && threadIdx.x == 0) *band_count = 0;

    int jbase = blockIdx.y * CHUNK;
    int ibase = blockIdx.x * 256;
#pragma unroll
    for (int rr = 0; rr < CHUNK / 256; rr++) {
        int r = rr * 256 + threadIdx.x;
        stage_row(db + (size_t)(jbase + r) * WS9, &s_dnh[r * KP], &s_dnl[r * KP]);
    }
    stage_row(patches + (size_t)(ibase + threadIdx.x) * WS9,
              &s_pnh[threadIdx.x * KP], &s_pnl[threadIdx.x * KP]);
    __syncthreads();

    int lane = threadIdx.x & 63;
    int wave = threadIdx.x >> 6;
    int col = lane & 31;
    int half = lane >> 5;
    int i0 = ibase + wave * 64;

    const bf16x8* Ph = (const bf16x8*)s_pnh;   // 2 frags per 16-elem row
    const bf16x8* Pl = (const bf16x8*)s_pnl;
    bf16x8 b_hi0 = Ph[(wave * 64 + col) * 2 + half];
    bf16x8 b_lo0 = Pl[(wave * 64 + col) * 2 + half];
    bf16x8 b_hi1 = Ph[(wave * 64 + 32 + col) * 2 + half];
    bf16x8 b_lo1 = Pl[(wave * 64 + 32 + col) * 2 + half];

    const bf16x8* Ah = (const bf16x8*)s_dnh;
    const bf16x8* Al = (const bf16x8*)s_dnl;

    f32x16 zc = {0.f,0.f,0.f,0.f,0.f,0.f,0.f,0.f,0.f,0.f,0.f,0.f,0.f,0.f,0.f,0.f};
    float rm0 = -3.0e38f, rm1 = -3.0e38f;

#pragma unroll 2
    for (int t = 0; t < TILES; ++t) {
        bf16x8 a_h = Ah[(t * 32 + col) * 2 + half];
        bf16x8 a_l = Al[(t * 32 + col) * 2 + half];
        f32x16 acc0 = __builtin_amdgcn_mfma_f32_32x32x16_bf16(a_h, b_hi0, zc, 0, 0, 0);
        acc0 = __builtin_amdgcn_mfma_f32_32x32x16_bf16(a_h, b_lo0, acc0, 0, 0, 0);
        acc0 = __builtin_amdgcn_mfma_f32_32x32x16_bf16(a_l, b_hi0, acc0, 0, 0, 0);
        f32x16 acc1 = __builtin_amdgcn_mfma_f32_32x32x16_bf16(a_h, b_hi1, zc, 0, 0, 0);
        acc1 = __builtin_amdgcn_mfma_f32_32x32x16_bf16(a_h, b_lo1, acc1, 0, 0, 0);
        acc1 = __builtin_amdgcn_mfma_f32_32x32x16_bf16(a_l, b_hi1, acc1, 0, 0, 0);
#pragma unroll
        for (int r = 0; r < 16; ++r) {
            rm0 = fmaxf(rm0, acc0[r]);
            rm1 = fmaxf(rm1, acc1[r]);
        }
    }
    rm0 = fmaxf(rm0, __shfl_xor(rm0, 32, 64));
    rm1 = fmaxf(rm1, __shfl_xor(rm1, 32, 64));
    int ti = half ? (i0 + 32 + col) : (i0 + col);
    partial[(size_t)blockIdx.y * NPATCH + ti] = half ? rm1 : rm0;
}

// K2: blocks [0,144) copy db rows to out (float4); blocks [144,208) classify:
// max over 32 chunk-partials, definite rows written, band -> global list.
__global__ __launch_bounds__(256) void k_finish(const float* __restrict__ patches,
                                                const float* __restrict__ db,
                                                const float* __restrict__ partial,
                                                float* __restrict__ out,
                                                int* __restrict__ band_list,
                                                int* __restrict__ band_count) {
    int b = blockIdx.x;
    if (b < COPY_BLOCKS) {
        int e = b * 256 + threadIdx.x;          // 36864 float4 = 147456 floats
        ((float4*)out)[e] = ((const float4*)db)[e];
        return;
    }
    int i = (b - COPY_BLOCKS) * 256 + threadIdx.x;
    float cosmax = partial[i];
#pragma unroll
    for (int c = 1; c < JCH; c++)
        cosmax = fmaxf(cosmax, partial[(size_t)c * NPATCH + i]);
    if (cosmax >= BAND_LO && cosmax < BAND_HI) {
        int idx = atomicAdd(band_count, 1);
        band_list[idx] = i;
        return;  // row written by phase 2
    }
    int hit = (cosmax >= BAND_HI) ? 1 : 0;
#pragma unroll
    for (int k = 0; k < WS9; k++)
        out[(size_t)(NDB + i) * WS9 + k] = hit ? 0.0f : patches[(size_t)i * WS9 + k];
}

// K3: exact numpy-mirror recheck for band patches (proven absmax=0).
// 256 blocks grid-stride over ~80 entries -> <=1 entry per block typically.
__global__ __launch_bounds__(256) void k_phase2(const float* __restrict__ patches,
                                                const float* __restrict__ db,
                                                const int* __restrict__ band_list,
                                                const int* __restrict__ band_count,
                                                float* __restrict__ out) {
    __shared__ float sp[WS9];
    __shared__ float snp;
    __shared__ int shit;
    int nb = *band_count;
    for (int idx = blockIdx.x; idx < nb; idx += gridDim.x) {
        int i = band_list[idx];
        if (threadIdx.x == 0) {
            float p[WS9];
            for (int k = 0; k < WS9; k++) { p[k] = patches[(size_t)i * WS9 + k]; sp[k] = p[k]; }
            snp = np_norm9(p);
            shit = 0;
        }
        __syncthreads();
        float p[WS9];
#pragma unroll
        for (int k = 0; k < WS9; k++) p[k] = sp[k];
        float npn = snp;
        int hit = 0;
        for (int j = (int)threadIdx.x; j < NDB; j += 256) {
            float d[WS9];
#pragma unroll
            for (int k = 0; k < WS9; k++) d[k] = db[(size_t)j * WS9 + k];
            float dot = 0.0f;
#pragma unroll
            for (int k = 0; k < WS9; k++) dot = fmaf(p[k], d[k], dot);
            float nd = np_norm9(d);
            float cs = dot / (npn * nd);          // IEEE fp32 divide
            if (!((double)cs < 0.9)) hit = 1;     // numpy promotes to f64
        }
        if (hit) atomicOr(&shit, 1);
        __syncthreads();
        int m = shit;
        if (threadIdx.x < WS9)
            out[(size_t)(NDB + i) * WS9 + threadIdx.x] = m ? 0.0f : sp[threadIdx.x];
        __syncthreads();
    }
}

extern "C" void kernel_launch(void* const* d_in, const int* in_sizes, int n_in,
                              void* d_out, int out_size, void* d_ws, size_t ws_size,
                              hipStream_t stream) {
    const float* patches = (const float*)d_in[0];  // [16384][9]
    const float* db      = (const float*)d_in[1];  // [16384][9]
    float* out = (float*)d_out;                    // [32768][9]

    // ws layout: partial (JCH*NPATCH f32 = 2 MB) | band_list (64 KB) | band_count
    char* wsb = (char*)d_ws;
    float* partial    = (float*)wsb;
    int*   band_list  = (int*)(wsb + (size_t)JCH * NPATCH * 4);
    int*   band_count = (int*)(wsb + (size_t)JCH * NPATCH * 4 + (size_t)NPATCH * 4);

    k_phase1<<<dim3(NPATCH / 256, JCH), dim3(256), 0, stream>>>(patches, db,
                                                                partial, band_count);
    k_finish<<<dim3(COPY_BLOCKS + NPATCH / 256), dim3(256), 0, stream>>>(
        patches, db, partial, out, band_list, band_count);
    k_phase2<<<dim3(256), dim3(256), 0, stream>>>(patches, db, band_list, band_count, out);
}